// Round 8
// baseline (1193.859 us; speedup 1.0000x reference)
//
#include <hip/hip_runtime.h>

// ---------------------------------------------------------------------------
// LightGCN on MI355X — round 7: zero-global-atomic CSR build.
//
//  R6 post-mortem: deg_rank's 157us = 4M device atomics x ~32B memory-side
//  granule (op-count-bound; u8 packing didn't help). This round removes
//  global atomics entirely:
//   A) count_kernel  — grid (slice s, chunk c): scan chunk-c edges, count
//      endpoints in slice-s via LDS byte-packed atomics (60KB = 61440 nodes),
//      write dense partial counts pc[c][node] (u8, coalesced words).
//   B) reduce_kernel — byte-wise prefix over chunks: chunk_off[c][node],
//      deg[node] (deg<=255 so packed-byte adds never carry).
//   C) fill2_kernel  — re-scan per (s,c): LDS cursor gives in-chunk rank;
//      ci[rp[n] + chunk_off[c][n] + rank] = partner. Stores land in the
//      slice's L2-resident ci range. No rank2 buffer, no memsets.
//  SpMM pipeline unchanged from R6 (bf16 pre-scaled z recurrence, W=32
//  chunks, JIT z0 planes, fused final+epilogue).
// ---------------------------------------------------------------------------

#define BLK 256
#define SCAN_CHUNK 2048
#define SLICE_N 61440           // nodes per LDS slice (60KB of u8 counters)
#define NCHUNK 32               // edge chunks

typedef unsigned int u32;
typedef unsigned char u8;
typedef float __attribute__((ext_vector_type(4))) f32x4;

static inline int nblk(long long total) { return (int)((total + BLK - 1) / BLK); }

// round-to-nearest-even pack of two f32 into bf16x2
__device__ inline u32 pack_bf2(float lo, float hi) {
    u32 a = __float_as_uint(lo);
    u32 b = __float_as_uint(hi);
    a = a + 0x7fffu + ((a >> 16) & 1u);
    b = b + 0x7fffu + ((b >> 16) & 1u);
    return (a >> 16) | (b & 0xffff0000u);
}

__device__ inline void unpack_acc(uint4 w, float* a) {
    a[0] += __uint_as_float(w.x << 16);
    a[1] += __uint_as_float(w.x & 0xffff0000u);
    a[2] += __uint_as_float(w.y << 16);
    a[3] += __uint_as_float(w.y & 0xffff0000u);
    a[4] += __uint_as_float(w.z << 16);
    a[5] += __uint_as_float(w.z & 0xffff0000u);
    a[6] += __uint_as_float(w.w << 16);
    a[7] += __uint_as_float(w.w & 0xffff0000u);
}

__device__ inline void unpack8(uint4 w, float* a) {
    a[0] = __uint_as_float(w.x << 16);
    a[1] = __uint_as_float(w.x & 0xffff0000u);
    a[2] = __uint_as_float(w.y << 16);
    a[3] = __uint_as_float(w.y & 0xffff0000u);
    a[4] = __uint_as_float(w.z << 16);
    a[5] = __uint_as_float(w.z & 0xffff0000u);
    a[6] = __uint_as_float(w.w << 16);
    a[7] = __uint_as_float(w.w & 0xffff0000u);
}

// ---- phase A: per-(slice,chunk) LDS counting ------------------------------
__global__ void count_kernel(const int* __restrict__ uid,
                             const int* __restrict__ iid,
                             int E, int n_users, int ce, int nslice,
                             int nw4, u32* __restrict__ pc) {
    __shared__ u32 cnt[SLICE_N / 4];
    int s = blockIdx.x % nslice;
    int c = blockIdx.x / nslice;
    u32 base = (u32)s * SLICE_N;
    for (int i = threadIdx.x; i < SLICE_N / 4; i += BLK) cnt[i] = 0;
    __syncthreads();
    int e0 = c * ce, e1 = min(E, e0 + ce);
    for (int e = e0 + threadIdx.x; e < e1; e += BLK) {
        u32 u  = (u32)uid[e];
        u32 iN = (u32)(n_users + iid[e]);
        u32 du = u - base, di = iN - base;
        if (du < SLICE_N) atomicAdd(&cnt[du >> 2], 1u << (8u * (du & 3u)));
        if (di < SLICE_N) atomicAdd(&cnt[di >> 2], 1u << (8u * (di & 3u)));
    }
    __syncthreads();
    u32 w0 = base >> 2;
    u32 wend = min((u32)(SLICE_N / 4), (u32)(nw4 > (int)w0 ? nw4 - (int)w0 : 0));
    u32* dst = pc + (size_t)c * nw4 + w0;
    for (u32 i = threadIdx.x; i < wend; i += BLK) dst[i] = cnt[i];
}

// ---- phase B: byte-wise prefix over chunks --------------------------------
__global__ void reduce_kernel(const u32* __restrict__ pc,
                              u32* __restrict__ coff,
                              u32* __restrict__ deg8w, int nw4) {
    int w = blockIdx.x * BLK + threadIdx.x;
    if (w >= nw4) return;
    u32 run = 0;
    #pragma unroll
    for (int c = 0; c < NCHUNK; ++c) {
        u32 v = pc[(size_t)c * nw4 + w];
        coff[(size_t)c * nw4 + w] = run;
        run += v;               // byte-lanes never carry: deg <= 255
    }
    deg8w[w] = run;
}

__global__ void dinv_kernel(const u8* __restrict__ deg8,
                            float* __restrict__ dinv, int n_nodes) {
    int t = blockIdx.x * blockDim.x + threadIdx.x;
    if (t < n_nodes) dinv[t] = rsqrtf((float)deg8[t] + 1e-8f);
}

// ---- prefix scan over u8 degrees: rp[i+1] = incl_sum(deg8[0..i]) ---------
__global__ void scan1_kernel(const u8* __restrict__ deg8,
                             u32* __restrict__ rp, u32* __restrict__ bsum, int n) {
    __shared__ u32 ts[256];
    int tid = threadIdx.x;
    int base = blockIdx.x * SCAN_CHUNK + tid * 8;
    u32 v[8];
    u32 s = 0;
    #pragma unroll
    for (int i = 0; i < 8; ++i) {
        v[i] = (base + i < n) ? (u32)deg8[base + i] : 0u;
        s += v[i];
    }
    ts[tid] = s;
    __syncthreads();
    for (int off = 1; off < 256; off <<= 1) {
        u32 a = (tid >= off) ? ts[tid - off] : 0u;
        __syncthreads();
        ts[tid] += a;
        __syncthreads();
    }
    u32 run = (tid > 0) ? ts[tid - 1] : 0u;
    #pragma unroll
    for (int i = 0; i < 8; ++i) {
        run += v[i];
        if (base + i < n) rp[base + i + 1] = run;
    }
    if (tid == 255) bsum[blockIdx.x] = ts[255];
}

__global__ void scan2_kernel(u32* __restrict__ bsum, int nb) {
    __shared__ u32 s[1024];
    int tid = threadIdx.x;
    s[tid] = (tid < nb) ? bsum[tid] : 0u;
    __syncthreads();
    for (int off = 1; off < 1024; off <<= 1) {
        u32 a = (tid >= off) ? s[tid - off] : 0u;
        __syncthreads();
        s[tid] += a;
        __syncthreads();
    }
    if (tid < nb) bsum[tid] = (tid == 0) ? 0u : s[tid - 1];
}

__global__ void scan3_kernel(u32* __restrict__ rp,
                             const u32* __restrict__ bsum, int n) {
    int t = blockIdx.x * blockDim.x + threadIdx.x;
    if (t < n) rp[t + 1] += bsum[t / SCAN_CHUNK];
    if (t == 0) rp[0] = 0u;
}

// ---- phase C: atomic-free fill via LDS cursors ----------------------------
__global__ void fill2_kernel(const int* __restrict__ uid,
                             const int* __restrict__ iid,
                             const u32* __restrict__ rp,
                             const u8* __restrict__ coff,  // [NCHUNK][nw4*4]
                             int E, int n_users, int ce, int nslice,
                             int stride, int* __restrict__ ci) {
    __shared__ u32 cur[SLICE_N / 4];
    int s = blockIdx.x % nslice;
    int c = blockIdx.x / nslice;
    u32 base = (u32)s * SLICE_N;
    for (int i = threadIdx.x; i < SLICE_N / 4; i += BLK) cur[i] = 0;
    __syncthreads();
    const u8* co = coff + (size_t)c * stride;
    int e0 = c * ce, e1 = min(E, e0 + ce);
    for (int e = e0 + threadIdx.x; e < e1; e += BLK) {
        u32 u  = (u32)uid[e];
        u32 iN = (u32)(n_users + iid[e]);
        u32 du = u - base, di = iN - base;
        if (du < SLICE_N) {
            u32 sh = 8u * (du & 3u);
            u32 r = (atomicAdd(&cur[du >> 2], 1u << sh) >> sh) & 0xffu;
            ci[rp[u] + (u32)co[u] + r] = (int)iN;
        }
        if (di < SLICE_N) {
            u32 sh = 8u * (di & 3u);
            u32 r = (atomicAdd(&cur[di >> 2], 1u << sh) >> sh) & 0xffu;
            ci[rp[iN] + (u32)co[iN] + r] = (int)u;
        }
    }
}

// ---- z0 plane p: z0p[row] = bf16(dinv[row] * emb[row, 32p:32p+32]) --------
__global__ void z0_plane_kernel(const f32x4* __restrict__ uemb,
                                const f32x4* __restrict__ iemb,
                                const float* __restrict__ dinv,
                                uint4* __restrict__ z0p, int plane,
                                int n_users, int n_nodes) {
    long long t = (long long)blockIdx.x * blockDim.x + threadIdx.x;
    if (t >= (long long)n_nodes * 4) return;
    int row = (int)(t >> 2);
    int j4  = (int)(t & 3);
    const f32x4* src = (row < n_users)
                           ? uemb + (size_t)row * 16 + plane * 8 + j4 * 2
                           : iemb + (size_t)(row - n_users) * 16 + plane * 8 + j4 * 2;
    f32x4 p = __builtin_nontemporal_load(src);
    f32x4 q = __builtin_nontemporal_load(src + 1);
    float w = dinv[row];
    uint4 o;
    o.x = pack_bf2(w * p.x, w * p.y);
    o.y = pack_bf2(w * p.z, w * p.w);
    o.z = pack_bf2(w * q.x, w * q.y);
    o.w = pack_bf2(w * q.z, w * q.w);
    z0p[(size_t)row * 4 + j4] = o;
}

// ---- middle layers: dst = bf16( dinv^2 * sum_{c} src[c] ), 64B rows -------
__global__ void spmm_mid(const u32* __restrict__ rp,
                         const int* __restrict__ ci,
                         const float* __restrict__ dinv,
                         const uint4* __restrict__ src,
                         uint4* __restrict__ dst, int n_nodes) {
    long long t = (long long)blockIdx.x * blockDim.x + threadIdx.x;
    int row = (int)(t >> 2);
    if (row >= n_nodes) return;
    int j = (int)(t & 3);
    const uint4* sp = src + j;
    u32 k = rp[row], end = rp[row + 1];
    float a[8] = {0.f, 0.f, 0.f, 0.f, 0.f, 0.f, 0.f, 0.f};
    for (; k + 3 < end; k += 4) {
        int c0 = ci[k], c1 = ci[k + 1], c2 = ci[k + 2], c3 = ci[k + 3];
        uint4 w0 = sp[(size_t)c0 * 4];
        uint4 w1 = sp[(size_t)c1 * 4];
        uint4 w2 = sp[(size_t)c2 * 4];
        uint4 w3 = sp[(size_t)c3 * 4];
        unpack_acc(w0, a); unpack_acc(w1, a);
        unpack_acc(w2, a); unpack_acc(w3, a);
    }
    for (; k < end; ++k) {
        uint4 w0 = sp[(size_t)ci[k] * 4];
        unpack_acc(w0, a);
    }
    float dr = dinv[row];
    float s = dr * dr;
    uint4 o;
    o.x = pack_bf2(s * a[0], s * a[1]);
    o.y = pack_bf2(s * a[2], s * a[3]);
    o.z = pack_bf2(s * a[4], s * a[5]);
    o.w = pack_bf2(s * a[6], s * a[7]);
    dst[(size_t)row * 4 + j] = o;
}

// ---- layer 3 + fused epilogue (nontemporal out stores) --------------------
__global__ void spmm_final(const u32* __restrict__ rp,
                           const int* __restrict__ ci,
                           const float* __restrict__ dinv,
                           const uint4* __restrict__ z2,
                           const uint4* __restrict__ z1,
                           const uint4* __restrict__ z0p,
                           f32x4* __restrict__ out, int f4base, int n_nodes) {
    long long t = (long long)blockIdx.x * blockDim.x + threadIdx.x;
    int row = (int)(t >> 2);
    if (row >= n_nodes) return;
    int j = (int)(t & 3);
    const uint4* sp = z2 + j;
    u32 k = rp[row], end = rp[row + 1];
    float a[8] = {0.f, 0.f, 0.f, 0.f, 0.f, 0.f, 0.f, 0.f};
    for (; k + 3 < end; k += 4) {
        int c0 = ci[k], c1 = ci[k + 1], c2 = ci[k + 2], c3 = ci[k + 3];
        uint4 w0 = sp[(size_t)c0 * 4];
        uint4 w1 = sp[(size_t)c1 * 4];
        uint4 w2 = sp[(size_t)c2 * 4];
        uint4 w3 = sp[(size_t)c3 * 4];
        unpack_acc(w0, a); unpack_acc(w1, a);
        unpack_acc(w2, a); unpack_acc(w3, a);
    }
    for (; k < end; ++k) {
        uint4 w0 = sp[(size_t)ci[k] * 4];
        unpack_acc(w0, a);
    }
    float dr = dinv[row];
    float inv = 1.0f / dr;

    float v0[8], v1[8], v2[8];
    unpack8(z0p[(size_t)row * 4 + j], v0);
    unpack8(z1[(size_t)row * 4 + j], v1);
    unpack8(z2[(size_t)row * 4 + j], v2);

    float r[8];
    #pragma unroll
    for (int i = 0; i < 8; ++i)
        r[i] = 0.25f * ((v0[i] + v1[i] + v2[i]) * inv + dr * a[i]);

    size_t ob = (size_t)row * 16 + f4base + j * 2;
    f32x4 lo = {r[0], r[1], r[2], r[3]};
    f32x4 hi = {r[4], r[5], r[6], r[7]};
    __builtin_nontemporal_store(lo, out + ob);
    __builtin_nontemporal_store(hi, out + ob + 1);
}

// ---------------------------------------------------------------------------
extern "C" void kernel_launch(void* const* d_in, const int* in_sizes, int n_in,
                              void* d_out, int out_size, void* d_ws, size_t ws_size,
                              hipStream_t stream) {
    const float* uemb = (const float*)d_in[0];
    const float* iemb = (const float*)d_in[1];
    const int*   uid  = (const int*)d_in[2];
    const int*   iid  = (const int*)d_in[3];

    const int d = 64;
    int n_users = in_sizes[0] / d;
    int n_items = in_sizes[1] / d;
    int E       = in_sizes[2];
    int n_nodes = n_users + n_items;
    long long nnz = 2LL * E;

    int nw4 = (n_nodes + 3) / 4;            // u32 words of byte counters
    int nslice = (n_nodes + SLICE_N - 1) / SLICE_N;
    int ce = (E + NCHUNK - 1) / NCHUNK;     // edges per chunk
    int stride = nw4 * 4;                   // bytes per chunk row

    auto align256 = [](size_t x) { return (x + 255) & ~(size_t)255; };
    size_t rp_b   = align256((size_t)(n_nodes + 1) * 4);
    size_t dinv_b = align256((size_t)n_nodes * 4);
    size_t ci_b   = align256((size_t)nnz * 4);
    size_t bs_b   = align256(4096 * 4);
    size_t pc_b   = align256((size_t)NCHUNK * nw4 * 4);
    size_t deg_b  = align256((size_t)nw4 * 4);
    size_t z0_b   = align256((size_t)n_nodes * 128);   // 2 planes x 64B
    size_t z_b    = align256((size_t)n_nodes * 64);

    char* p = (char*)d_ws;
    u32*   rp    = (u32*)p;    p += rp_b;
    float* dinv  = (float*)p;  p += dinv_b;
    int*   ci    = (int*)p;    p += ci_b;
    u32*   bsum  = (u32*)p;    p += bs_b;
    u32*   pc    = (u32*)p;    p += pc_b;
    u32*   coff  = (u32*)p;    p += pc_b;
    u32*   deg8w = (u32*)p;    p += deg_b;
    uint4* z0    = (uint4*)p;  p += z0_b;
    uint4* z1    = (uint4*)p;  p += z_b;
    uint4* z2    = (uint4*)p;
    size_t plane4 = (size_t)n_nodes * 4;

    // ---- A: LDS-sliced counting (no global atomics, no memsets) ----
    count_kernel<<<nslice * NCHUNK, BLK, 0, stream>>>(
        uid, iid, E, n_users, ce, nslice, nw4, pc);

    // ---- B: chunk prefix + degree ----
    reduce_kernel<<<nblk(nw4), BLK, 0, stream>>>(pc, coff, deg8w, nw4);
    dinv_kernel<<<nblk(n_nodes), BLK, 0, stream>>>((const u8*)deg8w, dinv, n_nodes);

    // ---- prefix scan deg8 -> rp ----
    int nb = (n_nodes + SCAN_CHUNK - 1) / SCAN_CHUNK;
    scan1_kernel<<<nb, 256, 0, stream>>>((const u8*)deg8w, rp, bsum, n_nodes);
    scan2_kernel<<<1, 1024, 0, stream>>>(bsum, nb);
    scan3_kernel<<<nblk(n_nodes), BLK, 0, stream>>>(rp, bsum, n_nodes);

    // ---- C: atomic-free fill ----
    fill2_kernel<<<nslice * NCHUNK, BLK, 0, stream>>>(
        uid, iid, rp, (const u8*)coff, E, n_users, ce, nslice, stride, ci);

    // ---- per feature-chunk (W=32): JIT z0 plane, then 3 gather layers ----
    f32x4* out4 = (f32x4*)d_out;
    long long nt = (long long)n_nodes * 4;
    for (int c = 0; c < 2; ++c) {
        uint4* z0p = z0 + (size_t)c * plane4;
        int f4base = c * 8;
        z0_plane_kernel<<<nblk(nt), BLK, 0, stream>>>(
            (const f32x4*)uemb, (const f32x4*)iemb, dinv, z0p, c,
            n_users, n_nodes);
        spmm_mid<<<nblk(nt), BLK, 0, stream>>>(rp, ci, dinv, z0p, z1, n_nodes);
        spmm_mid<<<nblk(nt), BLK, 0, stream>>>(rp, ci, dinv, z1, z2, n_nodes);
        spmm_final<<<nblk(nt), BLK, 0, stream>>>(rp, ci, dinv, z2, z1, z0p,
                                                 out4, f4base, n_nodes);
    }
}

// Round 9
// 996.723 us; speedup vs baseline: 1.1978x; 1.1978x over previous
//
#include <hip/hip_runtime.h>

// ---------------------------------------------------------------------------
// LightGCN on MI355X — round 8: zero-global-atomic CSR build, fixed.
//
//  R7 post-mortem: count+reduce (75us) beat deg_rank (157us), but fill2 was
//  344us: 60KB LDS -> 2 blocks/CU (14% occ), and slice%17 grid mapping spread
//  each slice's ci lines across XCDs -> 128MB of partial-line flushes.
//  Fixes: nslice=32 (SLICE_N=31252, 30.5KB LDS, 5 blocks/CU) and slice->XCD
//  pinning (s = blockIdx % 32 => XCD s%8 under round-robin dispatch) so each
//  slice's ci range assembles in ONE L2 and flushes once.
//  SpMM pipeline unchanged from R6 (bf16 pre-scaled z recurrence, W=32
//  chunks, JIT z0 planes, fused final+epilogue).
// ---------------------------------------------------------------------------

#define BLK 256
#define SCAN_CHUNK 2048
#define SLICE_N 31252           // nodes per LDS slice (mult of 4; 30.5KB)
#define NCHUNK 32               // edge chunks

typedef unsigned int u32;
typedef unsigned char u8;
typedef float __attribute__((ext_vector_type(4))) f32x4;

static inline int nblk(long long total) { return (int)((total + BLK - 1) / BLK); }

// round-to-nearest-even pack of two f32 into bf16x2
__device__ inline u32 pack_bf2(float lo, float hi) {
    u32 a = __float_as_uint(lo);
    u32 b = __float_as_uint(hi);
    a = a + 0x7fffu + ((a >> 16) & 1u);
    b = b + 0x7fffu + ((b >> 16) & 1u);
    return (a >> 16) | (b & 0xffff0000u);
}

__device__ inline void unpack_acc(uint4 w, float* a) {
    a[0] += __uint_as_float(w.x << 16);
    a[1] += __uint_as_float(w.x & 0xffff0000u);
    a[2] += __uint_as_float(w.y << 16);
    a[3] += __uint_as_float(w.y & 0xffff0000u);
    a[4] += __uint_as_float(w.z << 16);
    a[5] += __uint_as_float(w.z & 0xffff0000u);
    a[6] += __uint_as_float(w.w << 16);
    a[7] += __uint_as_float(w.w & 0xffff0000u);
}

__device__ inline void unpack8(uint4 w, float* a) {
    a[0] = __uint_as_float(w.x << 16);
    a[1] = __uint_as_float(w.x & 0xffff0000u);
    a[2] = __uint_as_float(w.y << 16);
    a[3] = __uint_as_float(w.y & 0xffff0000u);
    a[4] = __uint_as_float(w.z << 16);
    a[5] = __uint_as_float(w.z & 0xffff0000u);
    a[6] = __uint_as_float(w.w << 16);
    a[7] = __uint_as_float(w.w & 0xffff0000u);
}

// ---- phase A: per-(slice,chunk) LDS counting ------------------------------
// slice s = blockIdx % nslice; nslice % 8 == 0 so slice s is always served
// by XCD s%8 under round-robin dispatch (perf heuristic only).
__global__ void count_kernel(const int* __restrict__ uid,
                             const int* __restrict__ iid,
                             int E, int n_users, int ce, int nslice,
                             int nw4, u32* __restrict__ pc) {
    __shared__ u32 cnt[SLICE_N / 4];
    int s = blockIdx.x % nslice;
    int c = blockIdx.x / nslice;
    u32 base = (u32)s * SLICE_N;
    for (int i = threadIdx.x; i < SLICE_N / 4; i += BLK) cnt[i] = 0;
    __syncthreads();
    int e0 = c * ce, e1 = min(E, e0 + ce);
    for (int e = e0 + threadIdx.x; e < e1; e += BLK) {
        u32 u  = (u32)uid[e];
        u32 iN = (u32)(n_users + iid[e]);
        u32 du = u - base, di = iN - base;
        if (du < SLICE_N) atomicAdd(&cnt[du >> 2], 1u << (8u * (du & 3u)));
        if (di < SLICE_N) atomicAdd(&cnt[di >> 2], 1u << (8u * (di & 3u)));
    }
    __syncthreads();
    u32 w0 = base >> 2;
    u32 wend = min((u32)(SLICE_N / 4), (u32)(nw4 > (int)w0 ? nw4 - (int)w0 : 0));
    u32* dst = pc + (size_t)c * nw4 + w0;
    for (u32 i = threadIdx.x; i < wend; i += BLK) dst[i] = cnt[i];
}

// ---- phase B: byte-wise prefix over chunks --------------------------------
__global__ void reduce_kernel(const u32* __restrict__ pc,
                              u32* __restrict__ coff,
                              u32* __restrict__ deg8w, int nw4) {
    int w = blockIdx.x * BLK + threadIdx.x;
    if (w >= nw4) return;
    u32 run = 0;
    #pragma unroll
    for (int c = 0; c < NCHUNK; ++c) {
        u32 v = pc[(size_t)c * nw4 + w];
        coff[(size_t)c * nw4 + w] = run;
        run += v;               // byte-lanes never carry: deg <= 255
    }
    deg8w[w] = run;
}

__global__ void dinv_kernel(const u8* __restrict__ deg8,
                            float* __restrict__ dinv, int n_nodes) {
    int t = blockIdx.x * blockDim.x + threadIdx.x;
    if (t < n_nodes) dinv[t] = rsqrtf((float)deg8[t] + 1e-8f);
}

// ---- prefix scan over u8 degrees: rp[i+1] = incl_sum(deg8[0..i]) ---------
__global__ void scan1_kernel(const u8* __restrict__ deg8,
                             u32* __restrict__ rp, u32* __restrict__ bsum, int n) {
    __shared__ u32 ts[256];
    int tid = threadIdx.x;
    int base = blockIdx.x * SCAN_CHUNK + tid * 8;
    u32 v[8];
    u32 s = 0;
    #pragma unroll
    for (int i = 0; i < 8; ++i) {
        v[i] = (base + i < n) ? (u32)deg8[base + i] : 0u;
        s += v[i];
    }
    ts[tid] = s;
    __syncthreads();
    for (int off = 1; off < 256; off <<= 1) {
        u32 a = (tid >= off) ? ts[tid - off] : 0u;
        __syncthreads();
        ts[tid] += a;
        __syncthreads();
    }
    u32 run = (tid > 0) ? ts[tid - 1] : 0u;
    #pragma unroll
    for (int i = 0; i < 8; ++i) {
        run += v[i];
        if (base + i < n) rp[base + i + 1] = run;
    }
    if (tid == 255) bsum[blockIdx.x] = ts[255];
}

__global__ void scan2_kernel(u32* __restrict__ bsum, int nb) {
    __shared__ u32 s[1024];
    int tid = threadIdx.x;
    s[tid] = (tid < nb) ? bsum[tid] : 0u;
    __syncthreads();
    for (int off = 1; off < 1024; off <<= 1) {
        u32 a = (tid >= off) ? s[tid - off] : 0u;
        __syncthreads();
        s[tid] += a;
        __syncthreads();
    }
    if (tid < nb) bsum[tid] = (tid == 0) ? 0u : s[tid - 1];
}

__global__ void scan3_kernel(u32* __restrict__ rp,
                             const u32* __restrict__ bsum, int n) {
    int t = blockIdx.x * blockDim.x + threadIdx.x;
    if (t < n) rp[t + 1] += bsum[t / SCAN_CHUNK];
    if (t == 0) rp[0] = 0u;
}

// ---- phase C: atomic-free fill via LDS cursors, slice->XCD pinned ---------
__global__ void fill2_kernel(const int* __restrict__ uid,
                             const int* __restrict__ iid,
                             const u32* __restrict__ rp,
                             const u8* __restrict__ coff,  // [NCHUNK][nw4*4]
                             int E, int n_users, int ce, int nslice,
                             int stride, int* __restrict__ ci) {
    __shared__ u32 cur[SLICE_N / 4];
    int s = blockIdx.x % nslice;    // nslice % 8 == 0 -> XCD = s % 8 (heur.)
    int c = blockIdx.x / nslice;
    u32 base = (u32)s * SLICE_N;
    for (int i = threadIdx.x; i < SLICE_N / 4; i += BLK) cur[i] = 0;
    __syncthreads();
    const u8* co = coff + (size_t)c * stride;
    int e0 = c * ce, e1 = min(E, e0 + ce);
    for (int e = e0 + threadIdx.x; e < e1; e += BLK) {
        u32 u  = (u32)uid[e];
        u32 iN = (u32)(n_users + iid[e]);
        u32 du = u - base, di = iN - base;
        if (du < SLICE_N) {
            u32 sh = 8u * (du & 3u);
            u32 r = (atomicAdd(&cur[du >> 2], 1u << sh) >> sh) & 0xffu;
            ci[rp[u] + (u32)co[u] + r] = (int)iN;
        }
        if (di < SLICE_N) {
            u32 sh = 8u * (di & 3u);
            u32 r = (atomicAdd(&cur[di >> 2], 1u << sh) >> sh) & 0xffu;
            ci[rp[iN] + (u32)co[iN] + r] = (int)u;
        }
    }
}

// ---- z0 plane p: z0p[row] = bf16(dinv[row] * emb[row, 32p:32p+32]) --------
__global__ void z0_plane_kernel(const f32x4* __restrict__ uemb,
                                const f32x4* __restrict__ iemb,
                                const float* __restrict__ dinv,
                                uint4* __restrict__ z0p, int plane,
                                int n_users, int n_nodes) {
    long long t = (long long)blockIdx.x * blockDim.x + threadIdx.x;
    if (t >= (long long)n_nodes * 4) return;
    int row = (int)(t >> 2);
    int j4  = (int)(t & 3);
    const f32x4* src = (row < n_users)
                           ? uemb + (size_t)row * 16 + plane * 8 + j4 * 2
                           : iemb + (size_t)(row - n_users) * 16 + plane * 8 + j4 * 2;
    f32x4 p = __builtin_nontemporal_load(src);
    f32x4 q = __builtin_nontemporal_load(src + 1);
    float w = dinv[row];
    uint4 o;
    o.x = pack_bf2(w * p.x, w * p.y);
    o.y = pack_bf2(w * p.z, w * p.w);
    o.z = pack_bf2(w * q.x, w * q.y);
    o.w = pack_bf2(w * q.z, w * q.w);
    z0p[(size_t)row * 4 + j4] = o;
}

// ---- middle layers: dst = bf16( dinv^2 * sum_{c} src[c] ), 64B rows -------
__global__ void spmm_mid(const u32* __restrict__ rp,
                         const int* __restrict__ ci,
                         const float* __restrict__ dinv,
                         const uint4* __restrict__ src,
                         uint4* __restrict__ dst, int n_nodes) {
    long long t = (long long)blockIdx.x * blockDim.x + threadIdx.x;
    int row = (int)(t >> 2);
    if (row >= n_nodes) return;
    int j = (int)(t & 3);
    const uint4* sp = src + j;
    u32 k = rp[row], end = rp[row + 1];
    float a[8] = {0.f, 0.f, 0.f, 0.f, 0.f, 0.f, 0.f, 0.f};
    for (; k + 3 < end; k += 4) {
        int c0 = ci[k], c1 = ci[k + 1], c2 = ci[k + 2], c3 = ci[k + 3];
        uint4 w0 = sp[(size_t)c0 * 4];
        uint4 w1 = sp[(size_t)c1 * 4];
        uint4 w2 = sp[(size_t)c2 * 4];
        uint4 w3 = sp[(size_t)c3 * 4];
        unpack_acc(w0, a); unpack_acc(w1, a);
        unpack_acc(w2, a); unpack_acc(w3, a);
    }
    for (; k < end; ++k) {
        uint4 w0 = sp[(size_t)ci[k] * 4];
        unpack_acc(w0, a);
    }
    float dr = dinv[row];
    float s = dr * dr;
    uint4 o;
    o.x = pack_bf2(s * a[0], s * a[1]);
    o.y = pack_bf2(s * a[2], s * a[3]);
    o.z = pack_bf2(s * a[4], s * a[5]);
    o.w = pack_bf2(s * a[6], s * a[7]);
    dst[(size_t)row * 4 + j] = o;
}

// ---- layer 3 + fused epilogue (nontemporal out stores) --------------------
__global__ void spmm_final(const u32* __restrict__ rp,
                           const int* __restrict__ ci,
                           const float* __restrict__ dinv,
                           const uint4* __restrict__ z2,
                           const uint4* __restrict__ z1,
                           const uint4* __restrict__ z0p,
                           f32x4* __restrict__ out, int f4base, int n_nodes) {
    long long t = (long long)blockIdx.x * blockDim.x + threadIdx.x;
    int row = (int)(t >> 2);
    if (row >= n_nodes) return;
    int j = (int)(t & 3);
    const uint4* sp = z2 + j;
    u32 k = rp[row], end = rp[row + 1];
    float a[8] = {0.f, 0.f, 0.f, 0.f, 0.f, 0.f, 0.f, 0.f};
    for (; k + 3 < end; k += 4) {
        int c0 = ci[k], c1 = ci[k + 1], c2 = ci[k + 2], c3 = ci[k + 3];
        uint4 w0 = sp[(size_t)c0 * 4];
        uint4 w1 = sp[(size_t)c1 * 4];
        uint4 w2 = sp[(size_t)c2 * 4];
        uint4 w3 = sp[(size_t)c3 * 4];
        unpack_acc(w0, a); unpack_acc(w1, a);
        unpack_acc(w2, a); unpack_acc(w3, a);
    }
    for (; k < end; ++k) {
        uint4 w0 = sp[(size_t)ci[k] * 4];
        unpack_acc(w0, a);
    }
    float dr = dinv[row];
    float inv = 1.0f / dr;

    float v0[8], v1[8], v2[8];
    unpack8(z0p[(size_t)row * 4 + j], v0);
    unpack8(z1[(size_t)row * 4 + j], v1);
    unpack8(z2[(size_t)row * 4 + j], v2);

    float r[8];
    #pragma unroll
    for (int i = 0; i < 8; ++i)
        r[i] = 0.25f * ((v0[i] + v1[i] + v2[i]) * inv + dr * a[i]);

    size_t ob = (size_t)row * 16 + f4base + j * 2;
    f32x4 lo = {r[0], r[1], r[2], r[3]};
    f32x4 hi = {r[4], r[5], r[6], r[7]};
    __builtin_nontemporal_store(lo, out + ob);
    __builtin_nontemporal_store(hi, out + ob + 1);
}

// ---------------------------------------------------------------------------
extern "C" void kernel_launch(void* const* d_in, const int* in_sizes, int n_in,
                              void* d_out, int out_size, void* d_ws, size_t ws_size,
                              hipStream_t stream) {
    const float* uemb = (const float*)d_in[0];
    const float* iemb = (const float*)d_in[1];
    const int*   uid  = (const int*)d_in[2];
    const int*   iid  = (const int*)d_in[3];

    const int d = 64;
    int n_users = in_sizes[0] / d;
    int n_items = in_sizes[1] / d;
    int E       = in_sizes[2];
    int n_nodes = n_users + n_items;
    long long nnz = 2LL * E;

    int nw4 = (n_nodes + 3) / 4;            // u32 words of byte counters
    int nslice = (n_nodes + SLICE_N - 1) / SLICE_N;
    nslice = (nslice + 7) & ~7;             // multiple of 8 for XCD pinning
    int ce = (E + NCHUNK - 1) / NCHUNK;     // edges per chunk
    int stride = nw4 * 4;                   // bytes per chunk row

    auto align256 = [](size_t x) { return (x + 255) & ~(size_t)255; };
    size_t rp_b   = align256((size_t)(n_nodes + 1) * 4);
    size_t dinv_b = align256((size_t)n_nodes * 4);
    size_t ci_b   = align256((size_t)nnz * 4);
    size_t bs_b   = align256(4096 * 4);
    size_t pc_b   = align256((size_t)NCHUNK * nw4 * 4);
    size_t deg_b  = align256((size_t)nw4 * 4);
    size_t z0_b   = align256((size_t)n_nodes * 128);   // 2 planes x 64B
    size_t z_b    = align256((size_t)n_nodes * 64);

    char* p = (char*)d_ws;
    u32*   rp    = (u32*)p;    p += rp_b;
    float* dinv  = (float*)p;  p += dinv_b;
    int*   ci    = (int*)p;    p += ci_b;
    u32*   bsum  = (u32*)p;    p += bs_b;
    u32*   pc    = (u32*)p;    p += pc_b;
    u32*   coff  = (u32*)p;    p += pc_b;
    u32*   deg8w = (u32*)p;    p += deg_b;
    uint4* z0    = (uint4*)p;  p += z0_b;
    uint4* z1    = (uint4*)p;  p += z_b;
    uint4* z2    = (uint4*)p;
    size_t plane4 = (size_t)n_nodes * 4;

    // ---- A: LDS-sliced counting (no global atomics, no memsets) ----
    count_kernel<<<nslice * NCHUNK, BLK, 0, stream>>>(
        uid, iid, E, n_users, ce, nslice, nw4, pc);

    // ---- B: chunk prefix + degree ----
    reduce_kernel<<<nblk(nw4), BLK, 0, stream>>>(pc, coff, deg8w, nw4);
    dinv_kernel<<<nblk(n_nodes), BLK, 0, stream>>>((const u8*)deg8w, dinv, n_nodes);

    // ---- prefix scan deg8 -> rp ----
    int nb = (n_nodes + SCAN_CHUNK - 1) / SCAN_CHUNK;
    scan1_kernel<<<nb, 256, 0, stream>>>((const u8*)deg8w, rp, bsum, n_nodes);
    scan2_kernel<<<1, 1024, 0, stream>>>(bsum, nb);
    scan3_kernel<<<nblk(n_nodes), BLK, 0, stream>>>(rp, bsum, n_nodes);

    // ---- C: atomic-free fill, slice->XCD pinned ----
    fill2_kernel<<<nslice * NCHUNK, BLK, 0, stream>>>(
        uid, iid, rp, (const u8*)coff, E, n_users, ce, nslice, stride, ci);

    // ---- per feature-chunk (W=32): JIT z0 plane, then 3 gather layers ----
    f32x4* out4 = (f32x4*)d_out;
    long long nt = (long long)n_nodes * 4;
    for (int c = 0; c < 2; ++c) {
        uint4* z0p = z0 + (size_t)c * plane4;
        int f4base = c * 8;
        z0_plane_kernel<<<nblk(nt), BLK, 0, stream>>>(
            (const f32x4*)uemb, (const f32x4*)iemb, dinv, z0p, c,
            n_users, n_nodes);
        spmm_mid<<<nblk(nt), BLK, 0, stream>>>(rp, ci, dinv, z0p, z1, n_nodes);
        spmm_mid<<<nblk(nt), BLK, 0, stream>>>(rp, ci, dinv, z1, z2, n_nodes);
        spmm_final<<<nblk(nt), BLK, 0, stream>>>(rp, ci, dinv, z2, z1, z0p,
                                                 out4, f4base, n_nodes);
    }
}

// Round 10
// 711.953 us; speedup vs baseline: 1.6769x; 1.4000x over previous
//
#include <hip/hip_runtime.h>

// ---------------------------------------------------------------------------
// LightGCN on MI355X — round 9.
//  - CSR build reverted to R6 (deg_rank + XCD-sliced fill): measured cheaper
//    (227us) than the zero-atomic R7/R8 build (290us+). R8 lesson: LDS-cursor
//    fill pays a replicated edge scan that outweighs the atomic savings.
//  - SpMM now W=64 (full 128B bf16 rows): every gather is ONE fully-used
//    aligned TCC line (vs two 64B half-line gathers per row at W=32).
//    4M line-touches/layer instead of 8M, 3 dispatches instead of 6,
//    ci read once per layer. z0/z1/z2 = 3 x 128MB (ws >= 520MB per R0).
//  - bf16 pre-scaled recurrence z_{k+1} = dinv^2 * sum z_k[c], fused final
//    layer + epilogue, NT loads for emb / NT stores for out.
// ---------------------------------------------------------------------------

#define BLK 256
#define SCAN_CHUNK 2048
#define FILL_EPB 2048     // edges per fill block chunk

typedef unsigned int u32;
typedef unsigned char u8;
typedef float __attribute__((ext_vector_type(4))) f32x4;

static inline int nblk(long long total) { return (int)((total + BLK - 1) / BLK); }

// round-to-nearest-even pack of two f32 into bf16x2
__device__ inline u32 pack_bf2(float lo, float hi) {
    u32 a = __float_as_uint(lo);
    u32 b = __float_as_uint(hi);
    a = a + 0x7fffu + ((a >> 16) & 1u);
    b = b + 0x7fffu + ((b >> 16) & 1u);
    return (a >> 16) | (b & 0xffff0000u);
}

__device__ inline void unpack_acc(uint4 w, float* a) {
    a[0] += __uint_as_float(w.x << 16);
    a[1] += __uint_as_float(w.x & 0xffff0000u);
    a[2] += __uint_as_float(w.y << 16);
    a[3] += __uint_as_float(w.y & 0xffff0000u);
    a[4] += __uint_as_float(w.z << 16);
    a[5] += __uint_as_float(w.z & 0xffff0000u);
    a[6] += __uint_as_float(w.w << 16);
    a[7] += __uint_as_float(w.w & 0xffff0000u);
}

__device__ inline void unpack8(uint4 w, float* a) {
    a[0] = __uint_as_float(w.x << 16);
    a[1] = __uint_as_float(w.x & 0xffff0000u);
    a[2] = __uint_as_float(w.y << 16);
    a[3] = __uint_as_float(w.y & 0xffff0000u);
    a[4] = __uint_as_float(w.z << 16);
    a[5] = __uint_as_float(w.z & 0xffff0000u);
    a[6] = __uint_as_float(w.w << 16);
    a[7] = __uint_as_float(w.w & 0xffff0000u);
}

// ---- degree (u8-packed) + per-edge rank ----------------------------------
__global__ void deg_rank_kernel(const int* __restrict__ uid,
                                const int* __restrict__ iid,
                                int E, int n_users,
                                u32* __restrict__ degw,   // u8 counters, word-packed
                                u32* __restrict__ rank2) {
    int t = blockIdx.x * blockDim.x + threadIdx.x;
    if (t < E) {
        u32 u  = (u32)uid[t];
        u32 iN = (u32)(n_users + iid[t]);
        u32 su = 8u * (u & 3u), si = 8u * (iN & 3u);
        u32 r0 = atomicAdd(&degw[u >> 2],  1u << su);
        u32 r1 = atomicAdd(&degw[iN >> 2], 1u << si);
        r0 = (r0 >> su) & 0xffu;
        r1 = (r1 >> si) & 0xffu;
        rank2[t] = r0 | (r1 << 16);
    }
}

__global__ void dinv_kernel(const u8* __restrict__ deg8,
                            float* __restrict__ dinv, int n_nodes) {
    int t = blockIdx.x * blockDim.x + threadIdx.x;
    if (t < n_nodes) dinv[t] = rsqrtf((float)deg8[t] + 1e-8f);
}

// ---- prefix scan over u8 degrees: rp[i+1] = incl_sum(deg8[0..i]) ---------
__global__ void scan1_kernel(const u8* __restrict__ deg8,
                             u32* __restrict__ rp, u32* __restrict__ bsum, int n) {
    __shared__ u32 ts[256];
    int tid = threadIdx.x;
    int base = blockIdx.x * SCAN_CHUNK + tid * 8;
    u32 v[8];
    u32 s = 0;
    #pragma unroll
    for (int i = 0; i < 8; ++i) {
        v[i] = (base + i < n) ? (u32)deg8[base + i] : 0u;
        s += v[i];
    }
    ts[tid] = s;
    __syncthreads();
    for (int off = 1; off < 256; off <<= 1) {
        u32 a = (tid >= off) ? ts[tid - off] : 0u;
        __syncthreads();
        ts[tid] += a;
        __syncthreads();
    }
    u32 run = (tid > 0) ? ts[tid - 1] : 0u;
    #pragma unroll
    for (int i = 0; i < 8; ++i) {
        run += v[i];
        if (base + i < n) rp[base + i + 1] = run;
    }
    if (tid == 255) bsum[blockIdx.x] = ts[255];
}

__global__ void scan2_kernel(u32* __restrict__ bsum, int nb) {
    __shared__ u32 s[1024];
    int tid = threadIdx.x;
    s[tid] = (tid < nb) ? bsum[tid] : 0u;
    __syncthreads();
    for (int off = 1; off < 1024; off <<= 1) {
        u32 a = (tid >= off) ? s[tid - off] : 0u;
        __syncthreads();
        s[tid] += a;
        __syncthreads();
    }
    if (tid < nb) bsum[tid] = (tid == 0) ? 0u : s[tid - 1];
}

__global__ void scan3_kernel(u32* __restrict__ rp,
                             const u32* __restrict__ bsum, int n) {
    int t = blockIdx.x * blockDim.x + threadIdx.x;
    if (t < n) rp[t + 1] += bsum[t / SCAN_CHUNK];
    if (t == 0) rp[0] = 0u;
}

// ---- atomic-free, XCD-sliced CSR fill ------------------------------------
__global__ void fill_sliced_kernel(const int* __restrict__ uid,
                                   const int* __restrict__ iid,
                                   const u32* __restrict__ rank2,
                                   const u32* __restrict__ rp,
                                   int E, int n_users, int shift,
                                   int* __restrict__ ci) {
    int slice = blockIdx.x & 7;
    int chunk = blockIdx.x >> 3;
    int e0   = chunk * FILL_EPB;
    int eend = min(E, e0 + FILL_EPB);
    for (int e = e0 + threadIdx.x; e < eend; e += BLK) {
        int u  = uid[e];
        int iN = n_users + iid[e];
        u32 rr = rank2[e];
        if ((u >> shift) == slice)  ci[rp[u]  + (rr & 0xffffu)] = iN;
        if ((iN >> shift) == slice) ci[rp[iN] + (rr >> 16)]     = u;
    }
}

// ---- z0 = dinv * emb, bf16 [node][64] = 8 uint4 per 128B row --------------
__global__ void z0_full_kernel(const f32x4* __restrict__ uemb,
                               const f32x4* __restrict__ iemb,
                               const float* __restrict__ dinv,
                               uint4* __restrict__ z0,
                               int n_users, int n_nodes) {
    long long t = (long long)blockIdx.x * blockDim.x + threadIdx.x;
    if (t >= (long long)n_nodes * 8) return;
    int row = (int)(t >> 3);
    int j   = (int)(t & 7);
    const f32x4* src = (row < n_users)
                           ? uemb + (size_t)row * 16 + j * 2
                           : iemb + (size_t)(row - n_users) * 16 + j * 2;
    f32x4 p = __builtin_nontemporal_load(src);
    f32x4 q = __builtin_nontemporal_load(src + 1);
    float w = dinv[row];
    uint4 o;
    o.x = pack_bf2(w * p.x, w * p.y);
    o.y = pack_bf2(w * p.z, w * p.w);
    o.z = pack_bf2(w * q.x, w * q.y);
    o.w = pack_bf2(w * q.z, w * q.w);
    z0[(size_t)row * 8 + j] = o;
}

// ---- middle layers: dst = bf16( dinv^2 * sum_{c} src[c] ), 128B rows ------
// 8 lanes per row, one uint4 (8 bf16) per lane per edge: every gather is one
// fully-used, aligned 128B TCC line.
__global__ void spmm_mid64(const u32* __restrict__ rp,
                           const int* __restrict__ ci,
                           const float* __restrict__ dinv,
                           const uint4* __restrict__ src,
                           uint4* __restrict__ dst, int n_nodes) {
    long long t = (long long)blockIdx.x * blockDim.x + threadIdx.x;
    int row = (int)(t >> 3);
    if (row >= n_nodes) return;
    int j = (int)(t & 7);
    const uint4* sp = src + j;
    u32 k = rp[row], end = rp[row + 1];
    float a[8] = {0.f, 0.f, 0.f, 0.f, 0.f, 0.f, 0.f, 0.f};
    for (; k + 3 < end; k += 4) {
        int c0 = ci[k], c1 = ci[k + 1], c2 = ci[k + 2], c3 = ci[k + 3];
        uint4 w0 = sp[(size_t)c0 * 8];
        uint4 w1 = sp[(size_t)c1 * 8];
        uint4 w2 = sp[(size_t)c2 * 8];
        uint4 w3 = sp[(size_t)c3 * 8];
        unpack_acc(w0, a); unpack_acc(w1, a);
        unpack_acc(w2, a); unpack_acc(w3, a);
    }
    for (; k < end; ++k) {
        uint4 w0 = sp[(size_t)ci[k] * 8];
        unpack_acc(w0, a);
    }
    float dr = dinv[row];
    float s = dr * dr;
    uint4 o;
    o.x = pack_bf2(s * a[0], s * a[1]);
    o.y = pack_bf2(s * a[2], s * a[3]);
    o.z = pack_bf2(s * a[4], s * a[5]);
    o.w = pack_bf2(s * a[6], s * a[7]);
    dst[(size_t)row * 8 + j] = o;
}

// ---- layer 3 + fused epilogue (nontemporal out stores) --------------------
__global__ void spmm_final64(const u32* __restrict__ rp,
                             const int* __restrict__ ci,
                             const float* __restrict__ dinv,
                             const uint4* __restrict__ z2,
                             const uint4* __restrict__ z1,
                             const uint4* __restrict__ z0,
                             f32x4* __restrict__ out, int n_nodes) {
    long long t = (long long)blockIdx.x * blockDim.x + threadIdx.x;
    int row = (int)(t >> 3);
    if (row >= n_nodes) return;
    int j = (int)(t & 7);
    const uint4* sp = z2 + j;
    u32 k = rp[row], end = rp[row + 1];
    float a[8] = {0.f, 0.f, 0.f, 0.f, 0.f, 0.f, 0.f, 0.f};
    for (; k + 3 < end; k += 4) {
        int c0 = ci[k], c1 = ci[k + 1], c2 = ci[k + 2], c3 = ci[k + 3];
        uint4 w0 = sp[(size_t)c0 * 8];
        uint4 w1 = sp[(size_t)c1 * 8];
        uint4 w2 = sp[(size_t)c2 * 8];
        uint4 w3 = sp[(size_t)c3 * 8];
        unpack_acc(w0, a); unpack_acc(w1, a);
        unpack_acc(w2, a); unpack_acc(w3, a);
    }
    for (; k < end; ++k) {
        uint4 w0 = sp[(size_t)ci[k] * 8];
        unpack_acc(w0, a);
    }
    float dr = dinv[row];
    float inv = 1.0f / dr;

    float v0[8], v1[8], v2[8];
    unpack8(z0[(size_t)row * 8 + j], v0);
    unpack8(z1[(size_t)row * 8 + j], v1);
    unpack8(z2[(size_t)row * 8 + j], v2);

    float r[8];
    #pragma unroll
    for (int i = 0; i < 8; ++i)
        r[i] = 0.25f * ((v0[i] + v1[i] + v2[i]) * inv + dr * a[i]);

    size_t ob = (size_t)row * 16 + j * 2;
    f32x4 lo = {r[0], r[1], r[2], r[3]};
    f32x4 hi = {r[4], r[5], r[6], r[7]};
    __builtin_nontemporal_store(lo, out + ob);
    __builtin_nontemporal_store(hi, out + ob + 1);
}

// ---------------------------------------------------------------------------
extern "C" void kernel_launch(void* const* d_in, const int* in_sizes, int n_in,
                              void* d_out, int out_size, void* d_ws, size_t ws_size,
                              hipStream_t stream) {
    const float* uemb = (const float*)d_in[0];
    const float* iemb = (const float*)d_in[1];
    const int*   uid  = (const int*)d_in[2];
    const int*   iid  = (const int*)d_in[3];

    const int d = 64;
    int n_users = in_sizes[0] / d;
    int n_items = in_sizes[1] / d;
    int E       = in_sizes[2];
    int n_nodes = n_users + n_items;
    long long nnz = 2LL * E;

    auto align256 = [](size_t x) { return (x + 255) & ~(size_t)255; };
    size_t deg_b  = align256((size_t)n_nodes + 4);       // u8 counters
    size_t rp_b   = align256((size_t)(n_nodes + 1) * 4);
    size_t dinv_b = align256((size_t)n_nodes * 4);
    size_t ci_b   = align256((size_t)nnz * 4);
    size_t rk_b   = align256((size_t)E * 4);
    size_t bs_b   = align256(4096 * 4);
    size_t z_b    = align256((size_t)n_nodes * 128);     // 64 bf16 per row

    char* p = (char*)d_ws;
    u32*   degw  = (u32*)p;    p += deg_b;
    u32*   rp    = (u32*)p;    p += rp_b;
    float* dinv  = (float*)p;  p += dinv_b;
    int*   ci    = (int*)p;    p += ci_b;
    u32*   rank2 = (u32*)p;    p += rk_b;
    u32*   bsum  = (u32*)p;    p += bs_b;
    uint4* z0    = (uint4*)p;  p += z_b;
    uint4* z1    = (uint4*)p;  p += z_b;
    uint4* z2    = (uint4*)p;

    // node-range slice shift for fill: slice = row >> shift in [0,8)
    int shift = 0;
    while (((n_nodes - 1) >> shift) >= 8) shift++;

    // ---- degrees (u8, + per-edge ranks), dinv ----
    hipMemsetAsync(degw, 0, (size_t)n_nodes + 4, stream);
    deg_rank_kernel<<<nblk(E), BLK, 0, stream>>>(uid, iid, E, n_users, degw, rank2);
    dinv_kernel<<<nblk(n_nodes), BLK, 0, stream>>>((const u8*)degw, dinv, n_nodes);

    // ---- prefix scan deg8 -> rp ----
    int nb = (n_nodes + SCAN_CHUNK - 1) / SCAN_CHUNK;
    scan1_kernel<<<nb, 256, 0, stream>>>((const u8*)degw, rp, bsum, n_nodes);
    scan2_kernel<<<1, 1024, 0, stream>>>(bsum, nb);
    scan3_kernel<<<nblk(n_nodes), BLK, 0, stream>>>(rp, bsum, n_nodes);

    // ---- atomic-free XCD-sliced CSR fill ----
    int nchunks = (E + FILL_EPB - 1) / FILL_EPB;
    fill_sliced_kernel<<<nchunks * 8, BLK, 0, stream>>>(
        uid, iid, rank2, rp, E, n_users, shift, ci);

    // ---- full-width bf16 pipeline: z0, two mids, fused final ----
    long long nt = (long long)n_nodes * 8;
    z0_full_kernel<<<nblk(nt), BLK, 0, stream>>>(
        (const f32x4*)uemb, (const f32x4*)iemb, dinv, z0, n_users, n_nodes);
    spmm_mid64<<<nblk(nt), BLK, 0, stream>>>(rp, ci, dinv, z0, z1, n_nodes);
    spmm_mid64<<<nblk(nt), BLK, 0, stream>>>(rp, ci, dinv, z1, z2, n_nodes);
    spmm_final64<<<nblk(nt), BLK, 0, stream>>>(rp, ci, dinv, z2, z1, z0,
                                               (f32x4*)d_out, n_nodes);
}